// Round 9
// baseline (9025.557 us; speedup 1.0000x reference)
//
#include <hip/hip_runtime.h>
#include <hip/hip_bf16.h>

#define S_LEN 4096
#define HID   512          // per-direction hidden
#define E_DIM 512
#define G4    2048         // 4*H

__device__ __forceinline__ float fsig(float x) {
  return __fdividef(1.f, 1.f + __expf(-x));
}
__device__ __forceinline__ float ftanh_(float x) {
  return 1.f - __fdividef(2.f, __expf(2.f * x) + 1.f);
}
__device__ __forceinline__ unsigned int f2b(float f) {          // fp32 -> bf16 bits (RNE)
  unsigned int x = __float_as_uint(f);
  return (x + 0x7FFFu + ((x >> 16) & 1u)) >> 16;
}

// ---------------------------------------------------------------------------
// Phase 1: xp_dir[t][j] = sum_e emb[id(t)][e] * wih_dir[j][e] + b_dir[j]
// ---------------------------------------------------------------------------
__global__ __launch_bounds__(256) void proj_gemm(
    const int* __restrict__ ids, const float* __restrict__ emb,
    const float* __restrict__ wih_f, const float* __restrict__ wih_b,
    const float* __restrict__ b_f, const float* __restrict__ b_b,
    float* __restrict__ xp_f, float* __restrict__ xp_b)
{
  const int dir = blockIdx.z;
  const float* __restrict__ wih  = dir ? wih_b : wih_f;
  const float* __restrict__ bias = dir ? b_b : b_f;
  float* __restrict__ out = dir ? xp_b : xp_f;
  const int i0 = blockIdx.y * 128;
  const int j0 = blockIdx.x * 128;
  __shared__ __align__(16) float As[16 * 132];
  __shared__ __align__(16) float Bs[16 * 132];
  const int tid = threadIdx.x;
  const int ti = tid >> 4, tj = tid & 15;

  const int r0 = tid >> 2,        k40 = tid & 3;
  const int r1 = (tid + 256) >> 2, k41 = (tid + 256) & 3;
  const int id0 = ids[dir ? (S_LEN - 1 - (i0 + r0)) : (i0 + r0)];
  const int id1 = ids[dir ? (S_LEN - 1 - (i0 + r1)) : (i0 + r1)];
  const float* a0p = emb + (size_t)id0 * E_DIM + k40 * 4;
  const float* a1p = emb + (size_t)id1 * E_DIM + k41 * 4;
  const float* b0p = wih + (size_t)(j0 + r0) * E_DIM + k40 * 4;
  const float* b1p = wih + (size_t)(j0 + r1) * E_DIM + k41 * 4;

  float acc[8][8];
  #pragma unroll
  for (int x = 0; x < 8; ++x)
    #pragma unroll
    for (int y = 0; y < 8; ++y) acc[x][y] = 0.f;

  for (int k0 = 0; k0 < E_DIM; k0 += 16) {
    float4 va0 = *(const float4*)(a0p + k0);
    float4 va1 = *(const float4*)(a1p + k0);
    float4 vb0 = *(const float4*)(b0p + k0);
    float4 vb1 = *(const float4*)(b1p + k0);
    As[(k40*4+0)*132 + r0] = va0.x; As[(k40*4+1)*132 + r0] = va0.y;
    As[(k40*4+2)*132 + r0] = va0.z; As[(k40*4+3)*132 + r0] = va0.w;
    As[(k41*4+0)*132 + r1] = va1.x; As[(k41*4+1)*132 + r1] = va1.y;
    As[(k41*4+2)*132 + r1] = va1.z; As[(k41*4+3)*132 + r1] = va1.w;
    Bs[(k40*4+0)*132 + r0] = vb0.x; Bs[(k40*4+1)*132 + r0] = vb0.y;
    Bs[(k40*4+2)*132 + r0] = vb0.z; Bs[(k40*4+3)*132 + r0] = vb0.w;
    Bs[(k41*4+0)*132 + r1] = vb1.x; Bs[(k41*4+1)*132 + r1] = vb1.y;
    Bs[(k41*4+2)*132 + r1] = vb1.z; Bs[(k41*4+3)*132 + r1] = vb1.w;
    __syncthreads();
    const float4* As4 = (const float4*)As;   // row stride 33 float4
    const float4* Bs4 = (const float4*)Bs;
    #pragma unroll
    for (int k = 0; k < 16; ++k) {
      float4 al = As4[k*33 + ti];
      float4 ah = As4[k*33 + 16 + ti];
      float4 bl = Bs4[k*33 + tj];
      float4 bh = Bs4[k*33 + 16 + tj];
      float a[8] = {al.x, al.y, al.z, al.w, ah.x, ah.y, ah.z, ah.w};
      float b[8] = {bl.x, bl.y, bl.z, bl.w, bh.x, bh.y, bh.z, bh.w};
      #pragma unroll
      for (int x = 0; x < 8; ++x)
        #pragma unroll
        for (int y = 0; y < 8; ++y) acc[x][y] = fmaf(a[x], b[y], acc[x][y]);
    }
    __syncthreads();
  }
  float4 blo = *(const float4*)(bias + j0 + tj * 4);
  float4 bhi = *(const float4*)(bias + j0 + 64 + tj * 4);
  #pragma unroll
  for (int x = 0; x < 8; ++x) {
    int gi = i0 + ((x < 4) ? (ti * 4 + x) : (64 + ti * 4 + (x - 4)));
    float* orow = out + (size_t)gi * G4 + j0;
    float4 o0 = make_float4(acc[x][0] + blo.x, acc[x][1] + blo.y,
                            acc[x][2] + blo.z, acc[x][3] + blo.w);
    float4 o1 = make_float4(acc[x][4] + bhi.x, acc[x][5] + bhi.y,
                            acc[x][6] + bhi.z, acc[x][7] + bhi.w);
    *(float4*)(orow + tj * 4) = o0;
    *(float4*)(orow + 64 + tj * 4) = o1;
  }
}

// ---------------------------------------------------------------------------
// Phase 2: both LSTM recurrences. 32 WGs x 512 thr. WG (dir,g) owns 32 units.
// Blocking: thread (u_l = tid>>4, cs = tid&15) computes ALL 4 gates of
// unit u_l over cols [cs*32, cs*32+32). h lives in LDS as packed bf16
// (16 dwords per cs-chunk, padded stride 20 dwords -> 4x ds_read_b128).
// Reduction over cs: xor1/xor2 via DPP quad_perm, xor4/xor8 via shfl.
// Agent-scope tagged-word broadcast protocol unchanged (proven R3/R6).
// ---------------------------------------------------------------------------
#define DPPADD(a, CTRL) \
  a += __int_as_float(__builtin_amdgcn_mov_dpp(__float_as_int(a), CTRL, 0xf, 0xf, false));

__global__ __launch_bounds__(512, 2) void lstm_rec(
    const float* __restrict__ xp_f, const float* __restrict__ xp_b,
    const float* __restrict__ whh_f, const float* __restrict__ whh_b,
    float* __restrict__ hs, unsigned int* __restrict__ hslot)
{
  const int wg  = blockIdx.x;
  const int dir = wg >> 4, g = wg & 15;
  const float* __restrict__ xp  = dir ? xp_b  : xp_f;
  const float* __restrict__ whh = dir ? whh_b : whh_f;
  unsigned int* slot = hslot + dir * (4 * HID);
  const int tid = threadIdx.x;
  const int u_l = tid >> 4;          // local unit 0..31
  const int cs  = tid & 15;          // column segment (32 cols)
  const int U0  = g * 32;
  const int ownunit = U0 + u_l;
  const bool master = (cs == 0);

  // weights: 4 gate rows x 32 cols in registers
  float w0[32], w1[32], w2[32], w3[32];
  {
    const float4* p0 = (const float4*)(whh + (size_t)(0*HID + ownunit) * HID + cs * 32);
    const float4* p1 = (const float4*)(whh + (size_t)(1*HID + ownunit) * HID + cs * 32);
    const float4* p2 = (const float4*)(whh + (size_t)(2*HID + ownunit) * HID + cs * 32);
    const float4* p3 = (const float4*)(whh + (size_t)(3*HID + ownunit) * HID + cs * 32);
    #pragma unroll
    for (int q = 0; q < 8; ++q) {
      float4 a = p0[q]; w0[4*q]=a.x; w0[4*q+1]=a.y; w0[4*q+2]=a.z; w0[4*q+3]=a.w;
      float4 b = p1[q]; w1[4*q]=b.x; w1[4*q+1]=b.y; w1[4*q+2]=b.z; w1[4*q+3]=b.w;
      float4 c = p2[q]; w2[4*q]=c.x; w2[4*q+1]=c.y; w2[4*q+2]=c.z; w2[4*q+3]=c.w;
      float4 d = p3[q]; w3[4*q]=d.x; w3[4*q+1]=d.y; w3[4*q+2]=d.z; w3[4*q+3]=d.w;
    }
  }

  // packed-bf16 h, double-buffered. dword d (units 2d,2d+1) lives at padded
  // dword offset (d>>4)*20 + (d&15)  -> 16B-aligned chunks, stride 80B.
  __shared__ __align__(16) unsigned int hb_lds[2][320];
  for (int q = tid; q < 320; q += 512) hb_lds[0][q] = 0u;   // h_0 = 0
  __syncthreads();

  float c = 0.f;
  float xpv = (cs < 4) ? xp[(size_t)cs * HID + ownunit] : 0.f;  // xp[0][gate=cs row]
  int buf = 0;
  const unsigned int rel = (unsigned int)(tid - U0);   // <32u -> own unit

  for (int t = 0; t < S_LEN; ++t) {
    const uint4* hq = (const uint4*)(&hb_lds[buf][cs * 20]);
    uint4 d0 = hq[0], d1 = hq[1], d2 = hq[2], d3 = hq[3];
    float acc0 = 0.f, acc1 = 0.f, acc2 = 0.f, acc3 = 0.f;
    #define DW(dw, k) { \
      float lo = __uint_as_float((dw) << 16); \
      float hi = __uint_as_float((dw) & 0xffff0000u); \
      acc0 = fmaf(w0[2*(k)], lo, acc0); acc0 = fmaf(w0[2*(k)+1], hi, acc0); \
      acc1 = fmaf(w1[2*(k)], lo, acc1); acc1 = fmaf(w1[2*(k)+1], hi, acc1); \
      acc2 = fmaf(w2[2*(k)], lo, acc2); acc2 = fmaf(w2[2*(k)+1], hi, acc2); \
      acc3 = fmaf(w3[2*(k)], lo, acc3); acc3 = fmaf(w3[2*(k)+1], hi, acc3); }
    DW(d0.x, 0)  DW(d0.y, 1)  DW(d0.z, 2)  DW(d0.w, 3)
    DW(d1.x, 4)  DW(d1.y, 5)  DW(d1.z, 6)  DW(d1.w, 7)
    DW(d2.x, 8)  DW(d2.y, 9)  DW(d2.z, 10) DW(d2.w, 11)
    DW(d3.x, 12) DW(d3.y, 13) DW(d3.z, 14) DW(d3.w, 15)
    #undef DW

    // inject xp once per gate (lane cs==gate holds it)
    acc0 += (cs == 0) ? xpv : 0.f;
    acc1 += (cs == 1) ? xpv : 0.f;
    acc2 += (cs == 2) ? xpv : 0.f;
    acc3 += (cs == 3) ? xpv : 0.f;

    // reduce over 16 cs lanes: xor1, xor2 via DPP quad_perm; xor4, xor8 shfl
    DPPADD(acc0, 0xB1) DPPADD(acc1, 0xB1) DPPADD(acc2, 0xB1) DPPADD(acc3, 0xB1)
    DPPADD(acc0, 0x4E) DPPADD(acc1, 0x4E) DPPADD(acc2, 0x4E) DPPADD(acc3, 0x4E)
    acc0 += __shfl_xor(acc0, 4);  acc1 += __shfl_xor(acc1, 4);
    acc2 += __shfl_xor(acc2, 4);  acc3 += __shfl_xor(acc3, 4);
    acc0 += __shfl_xor(acc0, 8);  acc1 += __shfl_xor(acc1, 8);
    acc2 += __shfl_xor(acc2, 8);  acc3 += __shfl_xor(acc3, 8);

    // activations, uniform across the cs-group (no divergence)
    float i_ = fsig(acc0), f_ = fsig(acc1), g_ = ftanh_(acc2), o_ = fsig(acc3);
    c = f_ * c + i_ * g_;
    float h = o_ * ftanh_(c);
    unsigned int hbits = f2b(h);
    const unsigned int tagn = (unsigned int)(t + 1);

    if (master) {
      __hip_atomic_store(&slot[(tagn & 3) * HID + ownunit],
                         (tagn << 16) | hbits,
                         __ATOMIC_RELAXED, __HIP_MEMORY_SCOPE_AGENT);
      const int trow = dir ? (S_LEN - 1 - t) : t;
      hs[(size_t)trow * 1024 + dir * HID + ownunit] = h;
      unsigned short* hp = (unsigned short*)&hb_lds[buf ^ 1][0];
      int d = ownunit >> 1;
      hp[(((d >> 4) * 20 + (d & 15)) << 1) + (ownunit & 1)] = (unsigned short)hbits;
    }
    asm volatile("" ::: "memory");   // publish store issues before prefetch
    if (t + 1 < S_LEN) {
      if (cs < 4) xpv = xp[(size_t)(t + 1) * G4 + cs * HID + ownunit];
      if (rel >= 32u) {                       // remote unit `tid`: poll word
        unsigned int* pw = &slot[(tagn & 3) * HID + tid];
        unsigned int vv; int it = 0;
        for (;;) {
          vv = __hip_atomic_load(pw, __ATOMIC_RELAXED, __HIP_MEMORY_SCOPE_AGENT);
          if ((vv >> 16) == tagn) break;
          if (++it > 64) __builtin_amdgcn_s_sleep(1);
          if (it > (1 << 22)) { vv = tagn << 16; break; }   // bail: wrong, not hung
        }
        unsigned short* hp = (unsigned short*)&hb_lds[buf ^ 1][0];
        int d = tid >> 1;
        hp[(((d >> 4) * 20 + (d & 15)) << 1) + (tid & 1)] = (unsigned short)(vv & 0xFFFFu);
      }
      __syncthreads();
    }
    buf ^= 1;
  }
}

// ---------------------------------------------------------------------------
// Phase 3: em[t][tag] = lstm_out[t] . lin_w[tag] + lin_b[tag]
// ---------------------------------------------------------------------------
__global__ __launch_bounds__(512) void emis_kernel(
    const float* __restrict__ hs, const float* __restrict__ lin_w,
    const float* __restrict__ lin_b, float* __restrict__ em)
{
  __shared__ float4 rows[4096];   // 16 rows x 1024 fp32 = 64 KiB
  const int t0 = blockIdx.x * 16;
  const int tid = threadIdx.x;
  const float4* hs4 = (const float4*)(hs + (size_t)t0 * 1024);
  #pragma unroll
  for (int it = 0; it < 8; ++it) rows[it * 512 + tid] = hs4[it * 512 + tid];
  __syncthreads();
  const int r = tid >> 5, tag = tid & 31;
  const float4* w4 = (const float4*)(lin_w + (size_t)tag * 1024);
  float acc = 0.f;
  #pragma unroll 4
  for (int k = 0; k < 256; ++k) {
    float4 h = rows[r * 256 + k];
    float4 w = w4[k];
    acc += h.x * w.x + h.y * w.y + h.z * w.z + h.w * w.w;
  }
  em[(size_t)(t0 + r) * 32 + tag] = acc + lin_b[tag];
}

// ---------------------------------------------------------------------------
// Phase 4a: CRF chunk products (log-semiring), transposed output.
// ---------------------------------------------------------------------------
__global__ __launch_bounds__(1024) void crf_pass1(
    const float* __restrict__ em, const float* __restrict__ trans,
    float* __restrict__ Pt)
{
  __shared__ float tr[32 * 33];
  __shared__ float bufA[32 * 33], bufB[32 * 33];
  const int tid = threadIdx.x;
  const int i = tid >> 5, j = tid & 31;
  tr[i * 33 + j] = trans[i * 32 + j];
  const int c = blockIdx.x;
  const int t0 = (c == 0) ? 1 : c * 16;
  const int t1 = c * 16 + 16;
  bufA[i * 33 + j] = trans[i * 32 + j] + em[(size_t)t0 * 32 + j];
  __syncthreads();

  float* cur = bufA;
  float* nxt = bufB;
  for (int t = t0 + 1; t < t1; ++t) {
    float m = -1e30f;
    #pragma unroll
    for (int k = 0; k < 32; ++k)
      m = fmaxf(m, cur[i * 33 + k] + tr[k * 33 + j]);
    float s = 0.f;
    #pragma unroll
    for (int k = 0; k < 32; ++k)
      s += __expf(cur[i * 33 + k] + tr[k * 33 + j] - m);
    float nv = m + __logf(s) + em[(size_t)t * 32 + j];
    nxt[i * 33 + j] = nv;
    __syncthreads();
    float* tmp = cur; cur = nxt; nxt = tmp;
  }
  Pt[(size_t)c * 1024 + tid] = cur[(tid & 31) * 33 + (tid >> 5)];
}

// ---------------------------------------------------------------------------
// Phase 4b: scan 256 chunk matrices (wave 0) + gold score (wave 1); NLL out.
// ---------------------------------------------------------------------------
__global__ __launch_bounds__(128) void crf_pass2(
    const float* __restrict__ em, const float* __restrict__ Pt,
    const int* __restrict__ tgt, const float* __restrict__ st,
    const float* __restrict__ et, const float* __restrict__ trans,
    float* __restrict__ out)
{
  __shared__ float als[32];
  __shared__ float gold[2];
  const int tid = threadIdx.x;
  const int lane = tid & 63;
  const int wv = tid >> 6;

  if (wv == 1) {
    float se = 0.f;
    for (int t = lane; t < S_LEN; t += 64) {
      int tg = tgt[t];
      se += em[(size_t)t * 32 + tg];
      if (t + 1 < S_LEN) se += trans[tg * 32 + tgt[t + 1]];
    }
    #pragma unroll
    for (int m = 1; m < 64; m <<= 1) se += __shfl_xor(se, m);
    if (lane == 0) gold[0] = se + st[tgt[0]] + et[tgt[S_LEN - 1]];
  } else {
    const int jj = lane & 31;
    float a = st[jj] + em[jj];
    float4 P0, P1, P2, P3, P4, P5, P6, P7;
    {
      const float* pb = Pt + jj * 32;
      P0 = *(const float4*)(pb +  0); P1 = *(const float4*)(pb +  4);
      P2 = *(const float4*)(pb +  8); P3 = *(const float4*)(pb + 12);
      P4 = *(const float4*)(pb + 16); P5 = *(const float4*)(pb + 20);
      P6 = *(const float4*)(pb + 24); P7 = *(const float4*)(pb + 28);
    }
    for (int cc = 0; cc < 256; ++cc) {
      float4 N0, N1, N2, N3, N4, N5, N6, N7;
      if (cc < 255) {
        const float* pb = Pt + (size_t)(cc + 1) * 1024 + jj * 32;
        N0 = *(const float4*)(pb +  0); N1 = *(const float4*)(pb +  4);
        N2 = *(const float4*)(pb +  8); N3 = *(const float4*)(pb + 12);
        N4 = *(const float4*)(pb + 16); N5 = *(const float4*)(pb + 20);
        N6 = *(const float4*)(pb + 24); N7 = *(const float4*)(pb + 28);
      }
      als[jj] = a;   // duplicate write by lane and lane+32: same value
      float m = -1e30f;
      #define MAXQ(Q, b) \
        m = fmaxf(m, fmaxf(fmaxf(als[b+0] + Q.x, als[b+1] + Q.y), \
                           fmaxf(als[b+2] + Q.z, als[b+3] + Q.w)));
      MAXQ(P0, 0) MAXQ(P1, 4) MAXQ(P2, 8)  MAXQ(P3, 12)
      MAXQ(P4,16) MAXQ(P5,20) MAXQ(P6,24)  MAXQ(P7,28)
      float s = 0.f;
      #define SUMQ(Q, b) \
        s += __expf(als[b+0] + Q.x - m) + __expf(als[b+1] + Q.y - m) + \
             __expf(als[b+2] + Q.z - m) + __expf(als[b+3] + Q.w - m);
      SUMQ(P0, 0) SUMQ(P1, 4) SUMQ(P2, 8)  SUMQ(P3, 12)
      SUMQ(P4,16) SUMQ(P5,20) SUMQ(P6,24)  SUMQ(P7,28)
      #undef MAXQ
      #undef SUMQ
      a = m + __logf(s);
      P0 = N0; P1 = N1; P2 = N2; P3 = N3;
      P4 = N4; P5 = N5; P6 = N6; P7 = N7;
    }
    float x = (lane < 32) ? a + et[jj] : -1e30f;
    float mm = x;
    #pragma unroll
    for (int m2 = 1; m2 < 64; m2 <<= 1) mm = fmaxf(mm, __shfl_xor(mm, m2));
    float ss = (lane < 32) ? __expf(x - mm) : 0.f;
    #pragma unroll
    for (int m2 = 1; m2 < 64; m2 <<= 1) ss += __shfl_xor(ss, m2);
    if (lane == 0) gold[1] = mm + __logf(ss);
  }
  __syncthreads();
  if (tid == 0) out[0] = gold[1] - gold[0];
}

// ---------------------------------------------------------------------------
extern "C" void kernel_launch(void* const* d_in, const int* in_sizes, int n_in,
                              void* d_out, int out_size, void* d_ws, size_t ws_size,
                              hipStream_t stream) {
  const int*   ids   = (const int*)d_in[0];
  const int*   tgt   = (const int*)d_in[1];
  const float* emb   = (const float*)d_in[2];
  const float* wih_f = (const float*)d_in[3];
  const float* whh_f = (const float*)d_in[4];
  const float* b_f   = (const float*)d_in[5];
  const float* wih_b = (const float*)d_in[6];
  const float* whh_b = (const float*)d_in[7];
  const float* b_b   = (const float*)d_in[8];
  const float* lin_w = (const float*)d_in[9];
  const float* lin_b = (const float*)d_in[10];
  const float* st    = (const float*)d_in[11];
  const float* et    = (const float*)d_in[12];
  const float* trans = (const float*)d_in[13];

  float* xp_f = (float*)d_ws;                                   // 4096*2048
  float* xp_b = xp_f + (size_t)S_LEN * G4;                      // 4096*2048
  float* hs   = xp_b + (size_t)S_LEN * G4;                      // 4096*1024
  float* em   = hs   + (size_t)S_LEN * 1024;                    // 4096*32
  unsigned int* slot = (unsigned int*)(em + (size_t)S_LEN * 32);// 2*4*512
  float* Pt   = xp_f;   // reuse xp region (consumed before crf_pass1 runs)

  proj_gemm<<<dim3(16, 32, 2), dim3(256), 0, stream>>>(
      ids, emb, wih_f, wih_b, b_f, b_b, xp_f, xp_b);
  lstm_rec<<<dim3(32), dim3(512), 0, stream>>>(
      xp_f, xp_b, whh_f, whh_b, hs, slot);
  emis_kernel<<<dim3(256), dim3(512), 0, stream>>>(hs, lin_w, lin_b, em);
  crf_pass1<<<dim3(256), dim3(1024), 0, stream>>>(em, trans, Pt);
  crf_pass2<<<dim3(1), dim3(128), 0, stream>>>(em, Pt, tgt, st, et, trans,
                                               (float*)d_out);
}